// Round 1
// baseline (213.901 us; speedup 1.0000x reference)
//
#include <hip/hip_runtime.h>

#define F 32  // F_IN == F_OUT == 32

// Kernel 1: CSR row pointers from sorted COO rows via lower_bound.
__global__ __launch_bounds__(256) void csr_ptr_kernel(
    const int* __restrict__ rows, int* __restrict__ ptr, int E, int N) {
    int n = blockIdx.x * blockDim.x + threadIdx.x;
    if (n > N) return;
    int lo = 0, hi = E;
    while (lo < hi) {
        int mid = (lo + hi) >> 1;
        if (rows[mid] < n) lo = mid + 1; else hi = mid;
    }
    ptr[n] = lo;
}

// Kernel 2: one 64-lane wave per node.
//   lane = half (bit 5) x feature f (bits 0..4)
//   acc_f = sum over this half's edges of x[col*32 + f] * val
//   combine halves via shfl_xor(32), then fused 32x32 linear + bias + relu.
__global__ __launch_bounds__(256) void gnn_kernel(
    const float* __restrict__ x,
    const int*   __restrict__ rows,
    const int*   __restrict__ cols,
    const float* __restrict__ vals,
    const int*   __restrict__ row_ptr,   // may be null -> in-kernel binary search
    const float* __restrict__ W,         // [F_OUT, F_IN] row-major
    const float* __restrict__ bias,      // [F_OUT]
    float*       __restrict__ out,       // [N, F_OUT]
    int N, int E) {
    // W transposed in LDS: Wt[fi*F + fo]. At GEMM step fi, lanes f=0..31 read
    // consecutive addresses -> conflict-free (2 lanes/bank same-addr broadcast).
    __shared__ float Wt[F * F];
    int t = threadIdx.x;
    for (int i = t; i < F * F; i += 256) {
        int fo = i >> 5, fi = i & 31;
        Wt[fi * F + fo] = W[i];
    }
    __syncthreads();

    int lane = t & 63;
    int wave = t >> 6;
    int n = blockIdx.x * 4 + wave;
    if (n >= N) return;

    int f    = lane & 31;
    int half = lane >> 5;

    int start, end;
    if (row_ptr) {
        start = row_ptr[n];
        end   = row_ptr[n + 1];
    } else {
        // Fallback: half 0 searches n, half 1 searches n+1. Same data for all
        // lanes within a half -> broadcast loads, near-uniform branching.
        int target = n + half;
        int lo = 0, hi = E;
        while (lo < hi) {
            int mid = (lo + hi) >> 1;
            if (rows[mid] < target) lo = mid + 1; else hi = mid;
        }
        start = __shfl(lo, 0);
        end   = __shfl(lo, 32);
    }

    float acc = 0.0f;
    for (int e = start + half; e < end; e += 2) {
        int   c = cols[e];
        float v = vals[e];
        acc = fmaf(x[c * F + f], v, acc);   // wave reads 2 contiguous 128B rows
    }
    acc += __shfl_xor(acc, 32);             // combine the two halves

    // Fused linear: out[fo] = relu(b[fo] + sum_fi agg[fi] * W[fo][fi])
    float o = bias[f];
    #pragma unroll
    for (int fi = 0; fi < F; ++fi) {
        float a = __shfl(acc, fi);          // broadcast agg[fi] from lane fi
        o = fmaf(a, Wt[fi * F + f], o);
    }
    if (half == 0) out[n * F + f] = fmaxf(o, 0.0f);
}

extern "C" void kernel_launch(void* const* d_in, const int* in_sizes, int n_in,
                              void* d_out, int out_size, void* d_ws, size_t ws_size,
                              hipStream_t stream) {
    const float* x    = (const float*)d_in[0];
    const int*   rows = (const int*)  d_in[1];
    const int*   cols = (const int*)  d_in[2];
    const float* vals = (const float*)d_in[3];
    const float* W    = (const float*)d_in[4];
    const float* bias = (const float*)d_in[5];
    float*       out  = (float*)d_out;

    int N = in_sizes[0] / F;
    int E = in_sizes[1];

    int* row_ptr = nullptr;
    if (ws_size >= (size_t)(N + 1) * sizeof(int)) {
        row_ptr = (int*)d_ws;
        int threads = N + 1;
        csr_ptr_kernel<<<(threads + 255) / 256, 256, 0, stream>>>(rows, row_ptr, E, N);
    }

    gnn_kernel<<<(N + 3) / 4, 256, 0, stream>>>(
        x, rows, cols, vals, row_ptr, W, bias, out, N, E);
}

// Round 2
// 186.610 us; speedup vs baseline: 1.1462x; 1.1462x over previous
//
#include <hip/hip_runtime.h>

#define F 32  // F_IN == F_OUT == 32

// CSR row pointers from sorted COO rows via boundary scatter: thread e writes
// ptr[r] = e for every r in (rows[e-1], rows[e]]. O(E) coalesced reads,
// ~N total scattered writes. Covers all of ptr[0..N] (poisoned ws is fine).
__global__ __launch_bounds__(256) void csr_scatter_kernel(
    const int* __restrict__ rows, int* __restrict__ ptr, int E, int N) {
    int e = blockIdx.x * blockDim.x + threadIdx.x;
    if (e > E) return;
    int prev = (e == 0) ? -1 : rows[e - 1];
    int cur  = (e == E) ? N  : rows[e];
    for (int r = prev + 1; r <= cur; ++r) ptr[r] = e;
}

// One 64-lane wave per node. lane = g*8 + l:
//   g in [0,8): edge group (8 edges in flight, x2 unroll -> 16)
//   l in [0,8): feature quad, lane loads float4 = features 4l..4l+3
// Per edge the 8 lanes of a group read one contiguous 128B x-row.
// Reduction over groups: shfl_xor masks 8/16/32. GEMM: fully unrolled,
// compile-time shuffle sources (-> readlane) + broadcast LDS Wt reads.
__global__ __launch_bounds__(256) void gnn_kernel(
    const float* __restrict__ x,
    const int*   __restrict__ rows,   // only for ws-too-small fallback
    const int*   __restrict__ cols,
    const float* __restrict__ vals,
    const int*   __restrict__ row_ptr,  // null -> in-kernel binary search
    const float* __restrict__ W,        // [F_OUT, F_IN] row-major
    const float* __restrict__ bias,     // [F_OUT]
    float*       __restrict__ out,      // [N, F_OUT]
    int N, int E) {
    __shared__ float Wt[F * F];   // Wt[fi*32 + fo]
    __shared__ float bS[F];
    int t = threadIdx.x;
    for (int i = t; i < F * F; i += 256) {
        int fo = i >> 5, fi = i & 31;
        Wt[fi * F + fo] = W[i];
    }
    if (t < F) bS[t] = bias[t];
    __syncthreads();

    int lane = t & 63;
    int wave = t >> 6;
    int n = blockIdx.x * 4 + wave;
    if (n >= N) return;

    int g = lane >> 3;   // edge group
    int l = lane & 7;    // feature quad

    int start, end;
    if (row_ptr) {
        start = row_ptr[n];
        end   = row_ptr[n + 1];
    } else {
        int target = n + (lane >> 5);  // half 0 -> n, half 1 -> n+1
        int lo = 0, hi = E;
        while (lo < hi) {
            int mid = (lo + hi) >> 1;
            if (rows[mid] < target) lo = mid + 1; else hi = mid;
        }
        start = __shfl(lo, 0);
        end   = __shfl(lo, 32);
    }

    const float4* __restrict__ x4 = (const float4*)x;
    float4 acc0 = {0.f, 0.f, 0.f, 0.f};
    float4 acc1 = {0.f, 0.f, 0.f, 0.f};
    for (int e0 = start; e0 < end; e0 += 16) {
        int ea = e0 + g;
        int eb = ea + 8;
        if (ea < end) {                      // independent of eb branch ->
            int   c = cols[ea];              // both gathers issue together
            float v = vals[ea];
            float4 xr = x4[c * 8 + l];
            acc0.x = fmaf(xr.x, v, acc0.x);
            acc0.y = fmaf(xr.y, v, acc0.y);
            acc0.z = fmaf(xr.z, v, acc0.z);
            acc0.w = fmaf(xr.w, v, acc0.w);
        }
        if (eb < end) {
            int   c = cols[eb];
            float v = vals[eb];
            float4 xr = x4[c * 8 + l];
            acc1.x = fmaf(xr.x, v, acc1.x);
            acc1.y = fmaf(xr.y, v, acc1.y);
            acc1.z = fmaf(xr.z, v, acc1.z);
            acc1.w = fmaf(xr.w, v, acc1.w);
        }
    }
    acc0.x += acc1.x; acc0.y += acc1.y; acc0.z += acc1.z; acc0.w += acc1.w;

    #pragma unroll
    for (int m = 8; m < 64; m <<= 1) {
        acc0.x += __shfl_xor(acc0.x, m);
        acc0.y += __shfl_xor(acc0.y, m);
        acc0.z += __shfl_xor(acc0.z, m);
        acc0.w += __shfl_xor(acc0.w, m);
    }
    // Now every lane with quad l holds agg[4l..4l+3] in comp[].
    float comp[4] = {acc0.x, acc0.y, acc0.z, acc0.w};

    int fo = lane & 31;
    float o = bS[fo];
    #pragma unroll
    for (int fi = 0; fi < F; ++fi) {
        // Source lane fi>>2 and component fi&3 are compile-time constants.
        float av = __shfl(comp[fi & 3], fi >> 2);
        // Both halves read the SAME Wt address -> broadcast, conflict-free.
        o = fmaf(av, Wt[fi * F + fo], o);
    }
    if (lane < F) out[n * F + fo] = fmaxf(o, 0.0f);
}

extern "C" void kernel_launch(void* const* d_in, const int* in_sizes, int n_in,
                              void* d_out, int out_size, void* d_ws, size_t ws_size,
                              hipStream_t stream) {
    const float* x    = (const float*)d_in[0];
    const int*   rows = (const int*)  d_in[1];
    const int*   cols = (const int*)  d_in[2];
    const float* vals = (const float*)d_in[3];
    const float* W    = (const float*)d_in[4];
    const float* bias = (const float*)d_in[5];
    float*       out  = (float*)d_out;

    int N = in_sizes[0] / F;
    int E = in_sizes[1];

    int* row_ptr = nullptr;
    if (ws_size >= (size_t)(N + 1) * sizeof(int)) {
        row_ptr = (int*)d_ws;
        int threads = E + 1;
        csr_scatter_kernel<<<(threads + 255) / 256, 256, 0, stream>>>(rows, row_ptr, E, N);
    }

    gnn_kernel<<<(N + 3) / 4, 256, 0, stream>>>(
        x, rows, cols, vals, row_ptr, W, bias, out, N, E);
}

// Round 3
// 146.615 us; speedup vs baseline: 1.4589x; 1.2728x over previous
//
#include <hip/hip_runtime.h>

#define F 32  // F_IN == F_OUT == 32

// ---- bf16 helpers (manual RNE; avoids header dtype friction) ----
static __device__ __forceinline__ unsigned short f2bf(float f) {
    unsigned int u = __float_as_uint(f);
    u += 0x7FFF + ((u >> 16) & 1);      // round-to-nearest-even
    return (unsigned short)(u >> 16);
}
static __device__ __forceinline__ float bf2f(unsigned short s) {
    return __uint_as_float(((unsigned int)s) << 16);
}

// Kernel 1: CSR row pointers from sorted COO rows via boundary scatter.
__global__ __launch_bounds__(256) void csr_scatter_kernel(
    const int* __restrict__ rows, int* __restrict__ ptr, int E, int N) {
    int e = blockIdx.x * blockDim.x + threadIdx.x;
    if (e > E) return;
    int prev = (e == 0) ? -1 : rows[e - 1];
    int cur  = (e == E) ? N  : rows[e];
    for (int r = prev + 1; r <= cur; ++r) ptr[r] = e;
}

// Kernel 2: y = x @ W^T, stored bf16. Block = 256 = 8 nodes x 32 f_out.
__global__ __launch_bounds__(256) void xw_kernel(
    const float* __restrict__ x, const float* __restrict__ W,
    unsigned short* __restrict__ y, int N) {
    __shared__ float Wt[F * F];   // Wt[fi*32+fo] -> conflict-free reads below
    __shared__ float xs[8 * F];
    int t = threadIdx.x;
    #pragma unroll
    for (int k = 0; k < 4; ++k) {
        int i = t + k * 256;
        Wt[(i & 31) * F + (i >> 5)] = W[i];
    }
    int n0 = blockIdx.x * 8;
    int gi = n0 * F + t;
    xs[t] = (gi < N * F) ? x[gi] : 0.0f;
    __syncthreads();
    int nl = t >> 5, fo = t & 31;
    float acc = 0.0f;
    #pragma unroll
    for (int fi = 0; fi < F; ++fi)
        acc = fmaf(xs[nl * F + fi], Wt[fi * F + fo], acc);
    int n = n0 + nl;
    if (n < N) y[n * F + fo] = f2bf(acc);
}

// Kernel 3 (hot): wave = 8 nodes x 8 lanes. Lane l of group g holds features
// 4l..4l+3 (ushort4 = 8B; a group's 8 lanes cover one 64B bf16 row). Each
// group walks its node's edges with a 2-way unroll -> 16 gathers in flight
// per wave. NO shuffles, NO LDS. Epilogue: float4 bias+relu+store, coalesced
// (a wave writes 8 consecutive node rows = 1KB contiguous).
__global__ __launch_bounds__(256) void gnn_bf16_kernel(
    const unsigned short* __restrict__ y,
    const int*   __restrict__ cols,
    const float* __restrict__ vals,
    const int*   __restrict__ row_ptr,
    const float* __restrict__ bias,
    float*       __restrict__ out, int N) {
    int t = threadIdx.x;
    int lane = t & 63;
    int g = lane >> 3, l = lane & 7;
    int n = (blockIdx.x * 4 + (t >> 6)) * 8 + g;
    int start = 0, end = 0;
    if (n < N) { start = row_ptr[n]; end = row_ptr[n + 1]; }

    const ushort4* __restrict__ y8 = (const ushort4*)y;  // 8 x ushort4 per row
    float a0x = 0.f, a0y = 0.f, a0z = 0.f, a0w = 0.f;
    float a1x = 0.f, a1y = 0.f, a1z = 0.f, a1w = 0.f;
    for (int e = start; e < end; e += 2) {
        int   c0 = cols[e];
        float v0 = vals[e];
        ushort4 r0 = y8[c0 * 8 + l];
        a0x = fmaf(bf2f(r0.x), v0, a0x);
        a0y = fmaf(bf2f(r0.y), v0, a0y);
        a0z = fmaf(bf2f(r0.z), v0, a0z);
        a0w = fmaf(bf2f(r0.w), v0, a0w);
        if (e + 1 < end) {
            int   c1 = cols[e + 1];
            float v1 = vals[e + 1];
            ushort4 r1 = y8[c1 * 8 + l];
            a1x = fmaf(bf2f(r1.x), v1, a1x);
            a1y = fmaf(bf2f(r1.y), v1, a1y);
            a1z = fmaf(bf2f(r1.z), v1, a1z);
            a1w = fmaf(bf2f(r1.w), v1, a1w);
        }
    }
    if (n < N) {
        const float4 b4 = ((const float4*)bias)[l];
        float4 o;
        o.x = fmaxf(a0x + a1x + b4.x, 0.f);
        o.y = fmaf(0.f, 0.f, fmaxf(a0y + a1y + b4.y, 0.f));
        o.z = fmaxf(a0z + a1z + b4.z, 0.f);
        o.w = fmaxf(a0w + a1w + b4.w, 0.f);
        ((float4*)out)[n * 8 + l] = o;
    }
}

// ---- Fallback (ws too small for y): round-2 proven kernel ----
__global__ __launch_bounds__(256) void gnn_fp32_kernel(
    const float* __restrict__ x,
    const int*   __restrict__ rows,
    const int*   __restrict__ cols,
    const float* __restrict__ vals,
    const int*   __restrict__ row_ptr,
    const float* __restrict__ W,
    const float* __restrict__ bias,
    float*       __restrict__ out,
    int N, int E) {
    __shared__ float Wt[F * F];
    __shared__ float bS[F];
    int t = threadIdx.x;
    for (int i = t; i < F * F; i += 256)
        Wt[(i & 31) * F + (i >> 5)] = W[i];
    if (t < F) bS[t] = bias[t];
    __syncthreads();
    int lane = t & 63;
    int n = blockIdx.x * 4 + (t >> 6);
    if (n >= N) return;
    int g = lane >> 3, l = lane & 7;
    int start, end;
    if (row_ptr) { start = row_ptr[n]; end = row_ptr[n + 1]; }
    else {
        int target = n + (lane >> 5);
        int lo = 0, hi = E;
        while (lo < hi) { int mid = (lo + hi) >> 1; if (rows[mid] < target) lo = mid + 1; else hi = mid; }
        start = __shfl(lo, 0); end = __shfl(lo, 32);
    }
    const float4* __restrict__ x4 = (const float4*)x;
    float4 acc0 = {0,0,0,0}, acc1 = {0,0,0,0};
    for (int e0 = start; e0 < end; e0 += 16) {
        int ea = e0 + g, eb = ea + 8;
        if (ea < end) { int c = cols[ea]; float v = vals[ea]; float4 xr = x4[c * 8 + l];
            acc0.x = fmaf(xr.x, v, acc0.x); acc0.y = fmaf(xr.y, v, acc0.y);
            acc0.z = fmaf(xr.z, v, acc0.z); acc0.w = fmaf(xr.w, v, acc0.w); }
        if (eb < end) { int c = cols[eb]; float v = vals[eb]; float4 xr = x4[c * 8 + l];
            acc1.x = fmaf(xr.x, v, acc1.x); acc1.y = fmaf(xr.y, v, acc1.y);
            acc1.z = fmaf(xr.z, v, acc1.z); acc1.w = fmaf(xr.w, v, acc1.w); }
    }
    acc0.x += acc1.x; acc0.y += acc1.y; acc0.z += acc1.z; acc0.w += acc1.w;
    #pragma unroll
    for (int m = 8; m < 64; m <<= 1) {
        acc0.x += __shfl_xor(acc0.x, m); acc0.y += __shfl_xor(acc0.y, m);
        acc0.z += __shfl_xor(acc0.z, m); acc0.w += __shfl_xor(acc0.w, m);
    }
    float comp[4] = {acc0.x, acc0.y, acc0.z, acc0.w};
    int fo = lane & 31;
    float o = bS[fo];
    #pragma unroll
    for (int fi = 0; fi < F; ++fi)
        o = fmaf(__shfl(comp[fi & 3], fi >> 2), Wt[fi * F + fo], o);
    if (lane < F) out[n * F + fo] = fmaxf(o, 0.0f);
}

extern "C" void kernel_launch(void* const* d_in, const int* in_sizes, int n_in,
                              void* d_out, int out_size, void* d_ws, size_t ws_size,
                              hipStream_t stream) {
    const float* x    = (const float*)d_in[0];
    const int*   rows = (const int*)  d_in[1];
    const int*   cols = (const int*)  d_in[2];
    const float* vals = (const float*)d_in[3];
    const float* W    = (const float*)d_in[4];
    const float* bias = (const float*)d_in[5];
    float*       out  = (float*)d_out;

    int N = in_sizes[0] / F;
    int E = in_sizes[1];

    size_t rp_bytes = (size_t)(N + 1) * sizeof(int);
    size_t y_off    = (rp_bytes + 255) & ~(size_t)255;
    size_t need     = y_off + (size_t)N * F * sizeof(unsigned short);

    if (ws_size >= need) {
        int* row_ptr = (int*)d_ws;
        unsigned short* y = (unsigned short*)((char*)d_ws + y_off);
        csr_scatter_kernel<<<(E + 1 + 255) / 256, 256, 0, stream>>>(rows, row_ptr, E, N);
        xw_kernel<<<(N + 7) / 8, 256, 0, stream>>>(x, W, y, N);
        gnn_bf16_kernel<<<(N + 31) / 32, 256, 0, stream>>>(y, cols, vals, row_ptr, bias, out, N);
    } else {
        int* row_ptr = nullptr;
        if (ws_size >= rp_bytes) {
            row_ptr = (int*)d_ws;
            csr_scatter_kernel<<<(E + 1 + 255) / 256, 256, 0, stream>>>(rows, row_ptr, E, N);
        }
        gnn_fp32_kernel<<<(N + 3) / 4, 256, 0, stream>>>(
            x, rows, cols, vals, row_ptr, W, bias, out, N, E);
    }
}